// Round 7
// baseline (249.507 us; speedup 1.0000x reference)
//
#include <hip/hip_runtime.h>
#include <hip/hip_bf16.h>
#include <math.h>

#define BATCH 8
#define SEQ   2048
#define CH    256
#define NH    4
#define HD    64
// Q pre-scale: 64^-0.5 * log2(e)  (softmax runs in exp2 domain)
#define QSCALE 0.18033688011112042f

typedef short  bfrag __attribute__((ext_vector_type(8)));  // 8 bf16 (4 VGPRs)
typedef float  ffrag __attribute__((ext_vector_type(4)));  // 4 fp32 acc
typedef unsigned short ushort_t;

__device__ __forceinline__ unsigned short f2bf(float f) {
    union { float f; unsigned int u; } v; v.f = f;
    unsigned int r = v.u + 0x7FFF + ((v.u >> 16) & 1);   // RNE
    return (unsigned short)(r >> 16);
}
__device__ __forceinline__ unsigned int pack2(float a, float b) {
    const __hip_bfloat162 p = __float22bfloat162_rn(make_float2(a, b));
    return *(const unsigned int*)&p;
}

// ---------------------------------------------------------------------------
// Prep (weights only): Wqkv, Wproj -> transposed bf16 (W^T[n][k]).
// ---------------------------------------------------------------------------
#define WQN (CH * 3 * CH)            // 196608
#define WPN (CH * CH)                // 65536

__global__ __launch_bounds__(256) void prep_kernel(
    const float* __restrict__ Wqkv, const float* __restrict__ Wproj,
    ushort_t* __restrict__ WqkvT, ushort_t* __restrict__ WprojT) {
    const int fid = blockIdx.x * 256 + threadIdx.x;
    if (fid < WQN) {
        const int n = fid >> 8, k = fid & 255;
        WqkvT[n * CH + k] = f2bf(Wqkv[k * (3 * CH) + n]);
    } else if (fid < WQN + WPN) {
        const int i = fid - WQN;
        const int n = i >> 8, k = i & 255;
        WprojT[n * CH + k] = f2bf(Wproj[k * CH + n]);
    }
}

// ---------------------------------------------------------------------------
// QKV MFMA GEMM: x fp32 (16384x256) @ WqkvT^T + bqkv -> bf16 Q(*QSCALE),K
// [BH,T,D], V^T [BH,D,T]. 128x128 tile, 4 waves each 64x64, BK=64.
// Register prefetch of next k-step's x/Wt during MFMA compute.
// ---------------------------------------------------------------------------
#define GLS 72   // LDS row stride in ushorts (144 B, 16B-aligned)

__global__ __launch_bounds__(256) void qkv_mfma_kernel(
    const float* __restrict__ x, const ushort_t* __restrict__ Wt,
    const float* __restrict__ bias,
    ushort_t* __restrict__ Qb, ushort_t* __restrict__ Kb,
    ushort_t* __restrict__ Vtb) {
    __shared__ ushort_t smem[2 * 128 * GLS];   // As | Bs; reused as T[128][136]
    ushort_t* As = smem;
    ushort_t* Bs = smem + 128 * GLS;

    const int tid = threadIdx.x;
    const int wv  = tid >> 6;
    const int ln  = tid & 63;
    const int l15 = ln & 15;
    const int l4  = ln >> 4;
    const int wr  = wv >> 1;          // wave row 0..1
    const int wc  = wv & 1;           // wave col 0..1
    const int n0  = blockIdx.x * 128;
    const int m0  = blockIdx.y * 128;

    ffrag acc[4][4];
    #pragma unroll
    for (int i = 0; i < 4; i++)
        #pragma unroll
        for (int j = 0; j < 4; j++) acc[i][j] = (ffrag){0.f, 0.f, 0.f, 0.f};

    // prefetch registers: per r-slot 8 fp32 of x + 1 uint4 of Wt
    float4 pa0[4], pa1[4];
    uint4  pbv[4];
    #pragma unroll
    for (int r = 0; r < 4; r++) {
        const int fid = tid + r * 256;
        const int row = fid >> 3, c8 = (fid & 7) * 8;
        const float* xp = &x[(size_t)(m0 + row) * CH + c8];
        pa0[r] = *(const float4*)xp;
        pa1[r] = *(const float4*)(xp + 4);
        pbv[r] = *(const uint4*)&Wt[(n0 + row) * CH + c8];
    }

    for (int s = 0; s < 4; s++) {
        // commit prefetched tile to LDS (convert x fp32->bf16 here)
        #pragma unroll
        for (int r = 0; r < 4; r++) {
            const int fid = tid + r * 256;
            const int row = fid >> 3, c8 = (fid & 7) * 8;
            uint4 pk;
            pk.x = pack2(pa0[r].x, pa0[r].y); pk.y = pack2(pa0[r].z, pa0[r].w);
            pk.z = pack2(pa1[r].x, pa1[r].y); pk.w = pack2(pa1[r].z, pa1[r].w);
            *(uint4*)&As[row * GLS + c8] = pk;
            *(uint4*)&Bs[row * GLS + c8] = pbv[r];
        }
        __syncthreads();
        if (s < 3) {   // issue loads for next k-step (land during compute)
            const int k0 = (s + 1) * 64;
            #pragma unroll
            for (int r = 0; r < 4; r++) {
                const int fid = tid + r * 256;
                const int row = fid >> 3, c8 = (fid & 7) * 8;
                const float* xp = &x[(size_t)(m0 + row) * CH + k0 + c8];
                pa0[r] = *(const float4*)xp;
                pa1[r] = *(const float4*)(xp + 4);
                pbv[r] = *(const uint4*)&Wt[(n0 + row) * CH + k0 + c8];
            }
        }
        #pragma unroll
        for (int kk = 0; kk < 64; kk += 32) {
            bfrag a[4], b[4];
            #pragma unroll
            for (int i = 0; i < 4; i++)
                a[i] = *(const bfrag*)&As[(wr * 64 + i * 16 + l15) * GLS + kk + l4 * 8];
            #pragma unroll
            for (int j = 0; j < 4; j++)
                b[j] = *(const bfrag*)&Bs[(wc * 64 + j * 16 + l15) * GLS + kk + l4 * 8];
            #pragma unroll
            for (int i = 0; i < 4; i++)
                #pragma unroll
                for (int j = 0; j < 4; j++)
                    acc[i][j] = __builtin_amdgcn_mfma_f32_16x16x32_bf16(a[i], b[j], acc[i][j], 0, 0, 0);
        }
        __syncthreads();
    }

    const int mat = n0 >> 8;                 // block-uniform: 0=Q 1=K 2=V
    const int b   = m0 >> 11;                // block-uniform
    const int t0  = m0 & (SEQ - 1);
    ushort_t (*T)[136] = (ushort_t(*)[136])smem;

    if (mat < 2) {
        // Q/K: transpose to T[t_local][n_local], then coalesced [T,D] stores.
        const float sc = (mat == 0) ? QSCALE : 1.0f;
        #pragma unroll
        for (int j = 0; j < 4; j++) {
            const int n_local = wc * 64 + j * 16 + l15;
            const float bj = bias[n0 + n_local];
            #pragma unroll
            for (int i = 0; i < 4; i++) {
                const int m_base = wr * 64 + i * 16 + l4 * 4;
                #pragma unroll
                for (int r = 0; r < 4; r++)
                    T[m_base + r][n_local] = f2bf((acc[i][j][r] + bj) * sc);
            }
        }
        __syncthreads();
        ushort_t* dst = (mat == 0) ? Qb : Kb;
        #pragma unroll
        for (int rr = 0; rr < 8; rr++) {
            const int fid = tid + rr * 256;
            const int row = fid >> 4;            // t_local 0..127
            const int c8  = (fid & 15) * 8;      // n_local chunk
            const int n_glob = n0 + c8;
            const int h = (n_glob >> 6) & 3;
            const int d = n_glob & 63;
            *(uint4*)&dst[((size_t)((b * NH + h) * SEQ) + t0 + row) * HD + d] =
                *(const uint4*)&T[row][c8];
        }
    } else {
        // V: transpose to T[n_local][m_local], then coalesced [D,T] stores.
        #pragma unroll
        for (int j = 0; j < 4; j++) {
            const int n_local = wc * 64 + j * 16 + l15;
            const float bj = bias[n0 + n_local];
            #pragma unroll
            for (int i = 0; i < 4; i++) {
                const int m_base = wr * 64 + i * 16 + l4 * 4;
                ushort4 pk;
                pk.x = f2bf(acc[i][j][0] + bj);
                pk.y = f2bf(acc[i][j][1] + bj);
                pk.z = f2bf(acc[i][j][2] + bj);
                pk.w = f2bf(acc[i][j][3] + bj);
                *(ushort4*)&T[n_local][m_base] = pk;
            }
        }
        __syncthreads();
        #pragma unroll
        for (int rr = 0; rr < 8; rr++) {
            const int fid = tid + rr * 256;
            const int row = fid >> 4;            // n_local 0..127
            const int c8  = (fid & 15) * 8;      // m_local chunk
            const int n_glob = n0 + row;
            const int h = (n_glob >> 6) & 3;
            const int d = n_glob & 63;
            *(uint4*)&Vtb[(size_t)((b * NH + h) * HD + d) * SEQ + t0 + c8] =
                *(const uint4*)&T[row][c8];
        }
    }
}

// ---------------------------------------------------------------------------
// MFMA flash attention (causal), S^T form, exp2 softmax, BQ=128 (2 q-bands).
// K/V frags read once from LDS and reused by both bands -> LDS bytes/q ~halved.
// Double-buffered K/V (1 barrier/iter) + register prefetch one iter ahead.
// Grid 512: CU pairs long (qt=15-u) with short (qt=u) blocks; bh&7 -> XCD.
// ---------------------------------------------------------------------------
__global__ __launch_bounds__(256, 2) void attn_mfma_kernel(
    const ushort_t* __restrict__ Qb, const ushort_t* __restrict__ Kb,
    const ushort_t* __restrict__ Vtb, ushort_t* __restrict__ out) {
    __shared__ ushort_t Ps[128 * 64];      // P: 128 q-rows x 64 k (swizzled)
    __shared__ ushort_t KV[4 * 64 * 64];   // K0 | K1 | V0 | V1 (8 KB each)

    const int tid = threadIdx.x;
    const int wv  = tid >> 6;
    const int ln  = tid & 63;
    const int l15 = ln & 15;
    const int l4  = ln >> 4;
    const int e   = l15 & 7;

    const int L  = blockIdx.x;           // 0..511
    const int u  = L >> 5;               // 0..15
    const int bh = L & 31;
    const int qt = (u < 8) ? (15 - u) : (u - 8);   // longest-first
    const int b  = bh >> 2;
    const int h  = bh & 3;
    const int ktmax = 2 * qt + 1;

    // ---- Q fragments (B-operand), two 64-row bands ----
    const ushort_t* Qp0 = Qb + ((size_t)(bh * SEQ + qt * 128 + wv * 16 + l15)) * HD + l4 * 8;
    const bfrag bq00 = *(const bfrag*)Qp0;
    const bfrag bq01 = *(const bfrag*)(Qp0 + 32);
    const bfrag bq10 = *(const bfrag*)(Qp0 + 64 * HD);
    const bfrag bq11 = *(const bfrag*)(Qp0 + 64 * HD + 32);

    // ---- staging geometry ----
    const ushort_t* Kbase = Kb  + (size_t)bh * SEQ * HD;
    const ushort_t* Vbase = Vtb + (size_t)bh * HD * SEQ;
    const int srow  = tid >> 3;
    const int sc    = tid & 7;
    const int goffA = srow * 64 + sc * 8;
    const int voffA = srow * SEQ + sc * 8;
    const int soffA = srow * 64 + ((sc ^ (srow & 7)) * 8);

    const int kf0 = l15 * 64 + ((l4 ^ e) * 8);
    const int pf0 = (wv * 16 + l15) * 64 + ((l4 ^ e) * 8);
    const int pp  = e >> 1;
    const int pwb = (wv * 16 + l15) * 64 + (((l4 >> 1) ^ (e & 1)) * 8) + (l4 & 1) * 4;

    // ---- prologue: tile 0 -> LDS buf0 ; tile 1 -> regs ----
    uint4 kK0 = *(const uint4*)&Kbase[goffA];
    uint4 kK1 = *(const uint4*)&Kbase[goffA + 2048];
    uint4 kV0 = *(const uint4*)&Vbase[voffA];
    uint4 kV1 = *(const uint4*)&Vbase[voffA + 32 * SEQ];
    *(uint4*)&KV[soffA]               = kK0;
    *(uint4*)&KV[soffA + 2048]        = kK1;
    *(uint4*)&KV[8192 + soffA]        = kV0;
    *(uint4*)&KV[8192 + soffA + 2048] = kV1;
    kK0 = *(const uint4*)&Kbase[4096 + goffA];
    kK1 = *(const uint4*)&Kbase[4096 + goffA + 2048];
    kV0 = *(const uint4*)&Vbase[64 + voffA];
    kV1 = *(const uint4*)&Vbase[64 + voffA + 32 * SEQ];

    ffrag o0[4], o1[4];
    #pragma unroll
    for (int n = 0; n < 4; n++) {
        o0[n] = (ffrag){0.f, 0.f, 0.f, 0.f};
        o1[n] = (ffrag){0.f, 0.f, 0.f, 0.f};
    }
    float m0q = -INFINITY, l0q = 0.f;
    float m1q = -INFINITY, l1q = 0.f;
    const int rel = wv * 16 + l15;   // q position within the diagonal tile

    for (int kt = 0; kt <= ktmax; kt++) {
        if (kt > 0) {
            const int kb = (kt & 1) * 4096;
            *(uint4*)&KV[kb + soffA]               = kK0;
            *(uint4*)&KV[kb + soffA + 2048]        = kK1;
            *(uint4*)&KV[8192 + kb + soffA]        = kV0;
            *(uint4*)&KV[8192 + kb + soffA + 2048] = kV1;
            if (kt < ktmax) {
                const ushort_t* Kp  = Kbase + (kt + 1) * 4096;
                const ushort_t* Vtp = Vbase + (kt + 1) * 64;
                kK0 = *(const uint4*)&Kp[goffA];
                kK1 = *(const uint4*)&Kp[goffA + 2048];
                kV0 = *(const uint4*)&Vtp[voffA];
                kV1 = *(const uint4*)&Vtp[voffA + 32 * SEQ];
            }
        }
        __syncthreads();   // the ONLY barrier in the iteration

        const ushort_t* Kbuf = KV + (kt & 1) * 4096;
        const ushort_t* Vbuf = KV + 8192 + (kt & 1) * 4096;

        // ---- K frags read ONCE, reused by both q-bands ----
        bfrag ak0[4], ak1[4];
        #pragma unroll
        for (int n = 0; n < 4; n++) {
            ak0[n] = *(const bfrag*)&Kbuf[n * 1024 + kf0];
            ak1[n] = *(const bfrag*)&Kbuf[n * 1024 + (kf0 ^ 32)];
        }

        const bool act0 = (kt <= 2 * qt);     // band0 done after its diagonal
        const bool dia0 = (kt == 2 * qt);
        const bool dia1 = (kt == ktmax);

        // ---- band 0: S^T, softmax, P-pack, O-scale ----
        if (act0) {
            ffrag s[4];
            #pragma unroll
            for (int n = 0; n < 4; n++) {
                ffrag z = (ffrag){0.f, 0.f, 0.f, 0.f};
                z = __builtin_amdgcn_mfma_f32_16x16x32_bf16(ak0[n], bq00, z, 0, 0, 0);
                z = __builtin_amdgcn_mfma_f32_16x16x32_bf16(ak1[n], bq01, z, 0, 0, 0);
                s[n] = z;
            }
            if (dia0) {
                #pragma unroll
                for (int n = 0; n < 4; n++)
                    #pragma unroll
                    for (int r = 0; r < 4; r++)
                        if (n * 16 + l4 * 4 + r > rel) s[n][r] = -INFINITY;
            }
            float mx = s[0][0];
            #pragma unroll
            for (int n = 0; n < 4; n++)
                #pragma unroll
                for (int r = 0; r < 4; r++) mx = fmaxf(mx, s[n][r]);
            mx = fmaxf(mx, __shfl_xor(mx, 16));
            mx = fmaxf(mx, __shfl_xor(mx, 32));
            const float mn = fmaxf(m0q, mx);
            const float alpha = __builtin_amdgcn_exp2f(m0q - mn);
            m0q = mn;
            float rs = 0.f;
            #pragma unroll
            for (int n = 0; n < 4; n++)
                #pragma unroll
                for (int r = 0; r < 4; r++) {
                    const float p = __builtin_amdgcn_exp2f(s[n][r] - mn);
                    s[n][r] = p;
                    rs += p;
                }
            rs += __shfl_xor(rs, 16);
            rs += __shfl_xor(rs, 32);
            l0q = l0q * alpha + rs;
            #pragma unroll
            for (int n = 0; n < 4; n++) {
                uint2 pk;
                pk.x = pack2(s[n][0], s[n][1]);
                pk.y = pack2(s[n][2], s[n][3]);
                *(uint2*)&Ps[pwb + ((n ^ pp) << 4)] = pk;
            }
            #pragma unroll
            for (int r = 0; r < 4; r++) {
                const float ar = __shfl(alpha, l4 * 20 + r);
                #pragma unroll
                for (int n = 0; n < 4; n++) o0[n][r] *= ar;
            }
        }

        // ---- band 1 (always active) ----
        {
            ffrag s[4];
            #pragma unroll
            for (int n = 0; n < 4; n++) {
                ffrag z = (ffrag){0.f, 0.f, 0.f, 0.f};
                z = __builtin_amdgcn_mfma_f32_16x16x32_bf16(ak0[n], bq10, z, 0, 0, 0);
                z = __builtin_amdgcn_mfma_f32_16x16x32_bf16(ak1[n], bq11, z, 0, 0, 0);
                s[n] = z;
            }
            if (dia1) {
                #pragma unroll
                for (int n = 0; n < 4; n++)
                    #pragma unroll
                    for (int r = 0; r < 4; r++)
                        if (n * 16 + l4 * 4 + r > rel) s[n][r] = -INFINITY;
            }
            float mx = s[0][0];
            #pragma unroll
            for (int n = 0; n < 4; n++)
                #pragma unroll
                for (int r = 0; r < 4; r++) mx = fmaxf(mx, s[n][r]);
            mx = fmaxf(mx, __shfl_xor(mx, 16));
            mx = fmaxf(mx, __shfl_xor(mx, 32));
            const float mn = fmaxf(m1q, mx);
            const float alpha = __builtin_amdgcn_exp2f(m1q - mn);
            m1q = mn;
            float rs = 0.f;
            #pragma unroll
            for (int n = 0; n < 4; n++)
                #pragma unroll
                for (int r = 0; r < 4; r++) {
                    const float p = __builtin_amdgcn_exp2f(s[n][r] - mn);
                    s[n][r] = p;
                    rs += p;
                }
            rs += __shfl_xor(rs, 16);
            rs += __shfl_xor(rs, 32);
            l1q = l1q * alpha + rs;
            #pragma unroll
            for (int n = 0; n < 4; n++) {
                uint2 pk;
                pk.x = pack2(s[n][0], s[n][1]);
                pk.y = pack2(s[n][2], s[n][3]);
                *(uint2*)&Ps[4096 + pwb + ((n ^ pp) << 4)] = pk;
            }
            #pragma unroll
            for (int r = 0; r < 4; r++) {
                const float ar = __shfl(alpha, l4 * 20 + r);
                #pragma unroll
                for (int n = 0; n < 4; n++) o1[n][r] *= ar;
            }
        }

        // ---- PV: V frags read ONCE, reused by both bands ----
        bfrag ap00, ap01;
        if (act0) {
            ap00 = *(const bfrag*)&Ps[pf0];
            ap01 = *(const bfrag*)&Ps[pf0 ^ 32];
        }
        const bfrag ap10 = *(const bfrag*)&Ps[4096 + pf0];
        const bfrag ap11 = *(const bfrag*)&Ps[4096 + (pf0 ^ 32)];
        #pragma unroll
        for (int n = 0; n < 4; n++) {
            const bfrag bv0 = *(const bfrag*)&Vbuf[n * 1024 + kf0];
            const bfrag bv1 = *(const bfrag*)&Vbuf[n * 1024 + (kf0 ^ 32)];
            if (act0) {
                o0[n] = __builtin_amdgcn_mfma_f32_16x16x32_bf16(ap00, bv0, o0[n], 0, 0, 0);
                o0[n] = __builtin_amdgcn_mfma_f32_16x16x32_bf16(ap01, bv1, o0[n], 0, 0, 0);
            }
            o1[n] = __builtin_amdgcn_mfma_f32_16x16x32_bf16(ap10, bv0, o1[n], 0, 0, 0);
            o1[n] = __builtin_amdgcn_mfma_f32_16x16x32_bf16(ap11, bv1, o1[n], 0, 0, 0);
        }
    }

    // ---- normalize + store both bands (bf16, [B,T,C]) ----
    const int tg0 = qt * 128 + wv * 16 + l4 * 4;
    ushort_t* op = out + (size_t)(b * SEQ) * CH + h * HD;
    #pragma unroll
    for (int r = 0; r < 4; r++) {
        const float lr = __shfl(l0q, l4 * 20 + r);
        const float li = 1.0f / lr;
        #pragma unroll
        for (int n = 0; n < 4; n++)
            op[(size_t)(tg0 + r) * CH + n * 16 + l15] = f2bf(o0[n][r] * li);
    }
    #pragma unroll
    for (int r = 0; r < 4; r++) {
        const float lr = __shfl(l1q, l4 * 20 + r);
        const float li = 1.0f / lr;
        #pragma unroll
        for (int n = 0; n < 4; n++)
            op[(size_t)(tg0 + 64 + r) * CH + n * 16 + l15] = f2bf(o1[n][r] * li);
    }
}

// ---------------------------------------------------------------------------
// Proj MFMA GEMM: attn_b(16384x256) @ WprojT^T + bproj -> fp32 out.
// 64x64 tile (4 waves as 2x2 of 32x32), grid 1024 -> 4 blocks/CU.
// Double-buffered LDS (1 barrier/step) + register prefetch.
// ---------------------------------------------------------------------------
__global__ __launch_bounds__(256) void proj_mfma_kernel(
    const ushort_t* __restrict__ Ab, const ushort_t* __restrict__ Wt,
    const float* __restrict__ bias, float* __restrict__ O) {
    __shared__ ushort_t smem[2 * 128 * GLS];   // [buf][A(64) | B(64)]

    const int tid = threadIdx.x;
    const int wv  = tid >> 6;
    const int ln  = tid & 63;
    const int l15 = ln & 15;
    const int l4  = ln >> 4;
    const int wr  = wv >> 1;          // 0..1 -> 32-row band
    const int wc  = wv & 1;           // 0..1 -> 32-col band
    const int n0  = blockIdx.x * 64;
    const int m0  = blockIdx.y * 64;

    const int srow = tid >> 3;            // 0..31
    const int sc8  = (tid & 7) * 8;

    ffrag acc[2][2];
    #pragma unroll
    for (int i = 0; i < 2; i++)
        #pragma unroll
        for (int j = 0; j < 2; j++) acc[i][j] = (ffrag){0.f, 0.f, 0.f, 0.f};

    uint4 ra0, ra1, rb0, rb1;
    ra0 = *(const uint4*)&Ab[(size_t)(m0 + srow) * CH + sc8];
    ra1 = *(const uint4*)&Ab[(size_t)(m0 + 32 + srow) * CH + sc8];
    rb0 = *(const uint4*)&Wt[(n0 + srow) * CH + sc8];
    rb1 = *(const uint4*)&Wt[(n0 + 32 + srow) * CH + sc8];

    for (int s = 0; s < 4; s++) {
        ushort_t* As = smem + (s & 1) * (128 * GLS);
        ushort_t* Bs = As + 64 * GLS;
        *(uint4*)&As[srow * GLS + sc8]        = ra0;
        *(uint4*)&As[(32 + srow) * GLS + sc8] = ra1;
        *(uint4*)&Bs[srow * GLS + sc8]        = rb0;
        *(uint4*)&Bs[(32 + srow) * GLS + sc8] = rb1;
        __syncthreads();
        if (s < 3) {
            const int k0 = (s + 1) * 64;
            ra0 = *(const uint4*)&Ab[(size_t)(m0 + srow) * CH + k0 + sc8];
            ra1 = *(const uint4*)&Ab[(size_t)(m0 + 32 + srow) * CH + k0 + sc8];
            rb0 = *(const uint4*)&Wt[(n0 + srow) * CH + k0 + sc8];
            rb1 = *(const uint4*)&Wt[(n0 + 32 + srow) * CH + k0 + sc8];
        }
        #pragma unroll
        for (int kk = 0; kk < 64; kk += 32) {
            bfrag a[2], bfr[2];
            #pragma unroll
            for (int i = 0; i < 2; i++)
                a[i] = *(const bfrag*)&As[(wr * 32 + i * 16 + l15) * GLS + kk + l4 * 8];
            #pragma unroll
            for (int j = 0; j < 2; j++)
                bfr[j] = *(const bfrag*)&Bs[(wc * 32 + j * 16 + l15) * GLS + kk + l4 * 8];
            #pragma unroll
            for (int i = 0; i < 2; i++)
                #pragma unroll
                for (int j = 0; j < 2; j++)
                    acc[i][j] = __builtin_amdgcn_mfma_f32_16x16x32_bf16(a[i], bfr[j], acc[i][j], 0, 0, 0);
        }
        __syncthreads();
    }

    #pragma unroll
    for (int j = 0; j < 2; j++) {
        const int n = n0 + wc * 32 + j * 16 + l15;
        const float bj = bias[n];
        #pragma unroll
        for (int i = 0; i < 2; i++) {
            const int m = m0 + wr * 32 + i * 16 + l4 * 4;
            #pragma unroll
            for (int r = 0; r < 4; r++)
                O[(size_t)(m + r) * CH + n] = acc[i][j][r] + bj;
        }
    }
}

extern "C" void kernel_launch(void* const* d_in, const int* in_sizes, int n_in,
                              void* d_out, int out_size, void* d_ws, size_t ws_size,
                              hipStream_t stream) {
    const float* x     = (const float*)d_in[0];
    const float* Wqkv  = (const float*)d_in[1];
    const float* bqkv  = (const float*)d_in[2];
    const float* Wproj = (const float*)d_in[3];
    const float* bproj = (const float*)d_in[4];
    float* out = (float*)d_out;

    const size_t BHTD = (size_t)BATCH * NH * SEQ * HD;   // 4,194,304
    ushort_t* WqkvT  = (ushort_t*)d_ws;
    ushort_t* WprojT = WqkvT + (size_t)3 * CH * CH;
    ushort_t* Qb     = WprojT + (size_t)CH * CH;
    ushort_t* Kb     = Qb + BHTD;
    ushort_t* Vtb    = Kb + BHTD;
    ushort_t* attn_b = Vtb + BHTD;

    const int M = BATCH * SEQ;   // 16384

    {
        const int total = WQN + WPN;
        prep_kernel<<<(total + 255) / 256, 256, 0, stream>>>(Wqkv, Wproj, WqkvT, WprojT);
    }
    {
        dim3 grid((3 * CH) / 128, M / 128);
        qkv_mfma_kernel<<<grid, 256, 0, stream>>>(x, WqkvT, bqkv, Qb, Kb, Vtb);
    }
    {
        attn_mfma_kernel<<<dim3(512), 256, 0, stream>>>(Qb, Kb, Vtb, attn_b);
    }
    {
        dim3 grid(CH / 64, M / 64);
        proj_mfma_kernel<<<grid, 256, 0, stream>>>(attn_b, WprojT, bproj, out);
    }
}

// Round 8
// 149.011 us; speedup vs baseline: 1.6744x; 1.6744x over previous
//
#include <hip/hip_runtime.h>
#include <hip/hip_bf16.h>
#include <math.h>

#define BATCH 8
#define SEQ   2048
#define CH    256
#define NH    4
#define HD    64
#define NQB   (SEQ / 64)      // 32 query tiles of 64
// Q pre-scale: 64^-0.5 * log2(e)  (softmax runs in exp2 domain)
#define QSCALE 0.18033688011112042f

typedef short  bfrag __attribute__((ext_vector_type(8)));  // 8 bf16 (4 VGPRs)
typedef float  ffrag __attribute__((ext_vector_type(4)));  // 4 fp32 acc
typedef unsigned short ushort_t;

__device__ __forceinline__ unsigned short f2bf(float f) {
    union { float f; unsigned int u; } v; v.f = f;
    unsigned int r = v.u + 0x7FFF + ((v.u >> 16) & 1);   // RNE
    return (unsigned short)(r >> 16);
}
__device__ __forceinline__ unsigned int pack2(float a, float b) {
    const __hip_bfloat162 p = __float22bfloat162_rn(make_float2(a, b));
    return *(const unsigned int*)&p;
}

// ---------------------------------------------------------------------------
// Prep (weights only): Wqkv, Wproj -> transposed bf16 (W^T[n][k]).
// ---------------------------------------------------------------------------
#define WQN (CH * 3 * CH)            // 196608
#define WPN (CH * CH)                // 65536

__global__ __launch_bounds__(256) void prep_kernel(
    const float* __restrict__ Wqkv, const float* __restrict__ Wproj,
    ushort_t* __restrict__ WqkvT, ushort_t* __restrict__ WprojT) {
    const int fid = blockIdx.x * 256 + threadIdx.x;
    if (fid < WQN) {
        const int n = fid >> 8, k = fid & 255;
        WqkvT[n * CH + k] = f2bf(Wqkv[k * (3 * CH) + n]);
    } else if (fid < WQN + WPN) {
        const int i = fid - WQN;
        const int n = i >> 8, k = i & 255;
        WprojT[n * CH + k] = f2bf(Wproj[k * CH + n]);
    }
}

// ---------------------------------------------------------------------------
// QKV MFMA GEMM: x fp32 (16384x256) @ WqkvT^T + bqkv -> bf16 Q(*QSCALE),K
// [BH,T,D], V^T [BH,D,T]. 128x128 tile, 4 waves each 64x64, BK=64.
// Register prefetch of next k-step's x/Wt during MFMA compute.
// ---------------------------------------------------------------------------
#define GLS 72   // LDS row stride in ushorts (144 B, 16B-aligned)

__global__ __launch_bounds__(256) void qkv_mfma_kernel(
    const float* __restrict__ x, const ushort_t* __restrict__ Wt,
    const float* __restrict__ bias,
    ushort_t* __restrict__ Qb, ushort_t* __restrict__ Kb,
    ushort_t* __restrict__ Vtb) {
    __shared__ ushort_t smem[2 * 128 * GLS];   // As | Bs; reused as T[128][136]
    ushort_t* As = smem;
    ushort_t* Bs = smem + 128 * GLS;

    const int tid = threadIdx.x;
    const int wv  = tid >> 6;
    const int ln  = tid & 63;
    const int l15 = ln & 15;
    const int l4  = ln >> 4;
    const int wr  = wv >> 1;          // wave row 0..1
    const int wc  = wv & 1;           // wave col 0..1
    const int n0  = blockIdx.x * 128;
    const int m0  = blockIdx.y * 128;

    ffrag acc[4][4];
    #pragma unroll
    for (int i = 0; i < 4; i++)
        #pragma unroll
        for (int j = 0; j < 4; j++) acc[i][j] = (ffrag){0.f, 0.f, 0.f, 0.f};

    // prefetch registers: per r-slot 8 fp32 of x + 1 uint4 of Wt
    float4 pa0[4], pa1[4];
    uint4  pbv[4];
    #pragma unroll
    for (int r = 0; r < 4; r++) {
        const int fid = tid + r * 256;
        const int row = fid >> 3, c8 = (fid & 7) * 8;
        const float* xp = &x[(size_t)(m0 + row) * CH + c8];
        pa0[r] = *(const float4*)xp;
        pa1[r] = *(const float4*)(xp + 4);
        pbv[r] = *(const uint4*)&Wt[(n0 + row) * CH + c8];
    }

    for (int s = 0; s < 4; s++) {
        // commit prefetched tile to LDS (convert x fp32->bf16 here)
        #pragma unroll
        for (int r = 0; r < 4; r++) {
            const int fid = tid + r * 256;
            const int row = fid >> 3, c8 = (fid & 7) * 8;
            uint4 pk;
            pk.x = pack2(pa0[r].x, pa0[r].y); pk.y = pack2(pa0[r].z, pa0[r].w);
            pk.z = pack2(pa1[r].x, pa1[r].y); pk.w = pack2(pa1[r].z, pa1[r].w);
            *(uint4*)&As[row * GLS + c8] = pk;
            *(uint4*)&Bs[row * GLS + c8] = pbv[r];
        }
        __syncthreads();
        if (s < 3) {   // issue loads for next k-step (land during compute)
            const int k0 = (s + 1) * 64;
            #pragma unroll
            for (int r = 0; r < 4; r++) {
                const int fid = tid + r * 256;
                const int row = fid >> 3, c8 = (fid & 7) * 8;
                const float* xp = &x[(size_t)(m0 + row) * CH + k0 + c8];
                pa0[r] = *(const float4*)xp;
                pa1[r] = *(const float4*)(xp + 4);
                pbv[r] = *(const uint4*)&Wt[(n0 + row) * CH + k0 + c8];
            }
        }
        #pragma unroll
        for (int kk = 0; kk < 64; kk += 32) {
            bfrag a[4], b[4];
            #pragma unroll
            for (int i = 0; i < 4; i++)
                a[i] = *(const bfrag*)&As[(wr * 64 + i * 16 + l15) * GLS + kk + l4 * 8];
            #pragma unroll
            for (int j = 0; j < 4; j++)
                b[j] = *(const bfrag*)&Bs[(wc * 64 + j * 16 + l15) * GLS + kk + l4 * 8];
            #pragma unroll
            for (int i = 0; i < 4; i++)
                #pragma unroll
                for (int j = 0; j < 4; j++)
                    acc[i][j] = __builtin_amdgcn_mfma_f32_16x16x32_bf16(a[i], b[j], acc[i][j], 0, 0, 0);
        }
        __syncthreads();
    }

    const int mat = n0 >> 8;                 // block-uniform: 0=Q 1=K 2=V
    const int b   = m0 >> 11;                // block-uniform
    const int t0  = m0 & (SEQ - 1);
    ushort_t (*T)[136] = (ushort_t(*)[136])smem;

    if (mat < 2) {
        // Q/K: transpose to T[t_local][n_local], then coalesced [T,D] stores.
        const float sc = (mat == 0) ? QSCALE : 1.0f;
        #pragma unroll
        for (int j = 0; j < 4; j++) {
            const int n_local = wc * 64 + j * 16 + l15;
            const float bj = bias[n0 + n_local];
            #pragma unroll
            for (int i = 0; i < 4; i++) {
                const int m_base = wr * 64 + i * 16 + l4 * 4;
                #pragma unroll
                for (int r = 0; r < 4; r++)
                    T[m_base + r][n_local] = f2bf((acc[i][j][r] + bj) * sc);
            }
        }
        __syncthreads();
        ushort_t* dst = (mat == 0) ? Qb : Kb;
        #pragma unroll
        for (int rr = 0; rr < 8; rr++) {
            const int fid = tid + rr * 256;
            const int row = fid >> 4;            // t_local 0..127
            const int c8  = (fid & 15) * 8;      // n_local chunk
            const int n_glob = n0 + c8;
            const int h = (n_glob >> 6) & 3;
            const int d = n_glob & 63;
            *(uint4*)&dst[((size_t)((b * NH + h) * SEQ) + t0 + row) * HD + d] =
                *(const uint4*)&T[row][c8];
        }
    } else {
        // V: transpose to T[n_local][m_local], then coalesced [D,T] stores.
        #pragma unroll
        for (int j = 0; j < 4; j++) {
            const int n_local = wc * 64 + j * 16 + l15;
            const float bj = bias[n0 + n_local];
            #pragma unroll
            for (int i = 0; i < 4; i++) {
                const int m_base = wr * 64 + i * 16 + l4 * 4;
                ushort4 pk;
                pk.x = f2bf(acc[i][j][0] + bj);
                pk.y = f2bf(acc[i][j][1] + bj);
                pk.z = f2bf(acc[i][j][2] + bj);
                pk.w = f2bf(acc[i][j][3] + bj);
                *(ushort4*)&T[n_local][m_base] = pk;
            }
        }
        __syncthreads();
        #pragma unroll
        for (int rr = 0; rr < 8; rr++) {
            const int fid = tid + rr * 256;
            const int row = fid >> 4;            // n_local 0..127
            const int c8  = (fid & 15) * 8;      // m_local chunk
            const int n_glob = n0 + row;
            const int h = (n_glob >> 6) & 3;
            const int d = n_glob & 63;
            *(uint4*)&Vtb[(size_t)((b * NH + h) * HD + d) * SEQ + t0 + c8] =
                *(const uint4*)&T[row][c8];
        }
    }
}

// ---------------------------------------------------------------------------
// MFMA flash attention (causal), S^T formulation, exp2 softmax.
// Round-6 structure (best measured; round-7 BQ=128 spilled and regressed):
//  - BQ=64, double-buffered K/V in LDS: ONE barrier per K-tile iteration
//  - register prefetch one full iteration ahead of the LDS commit
//  - unpadded 64-ushort rows + XOR-16B-chunk swizzle (conflict-free)
//  - LDS exactly 40 KB -> 4 blocks/CU; Q frags loaded direct from global
//  - alpha / l broadcast via __shfl (no LDS arrays)
// ---------------------------------------------------------------------------
__global__ __launch_bounds__(256, 4) void attn_mfma_kernel(
    const ushort_t* __restrict__ Qb, const ushort_t* __restrict__ Kb,
    const ushort_t* __restrict__ Vtb, ushort_t* __restrict__ out) {
    __shared__ ushort_t Ps[64 * 64];       // P tiles (wave-private 16-row bands)
    __shared__ ushort_t KV[4 * 64 * 64];   // K0 | K1 | V0 | V1 (8 KB each)

    const int tid = threadIdx.x;
    const int wv  = tid >> 6;
    const int ln  = tid & 63;
    const int l15 = ln & 15;
    const int l4  = ln >> 4;
    const int e   = l15 & 7;

    const int L  = blockIdx.x;
    const int g  = L & 255;
    const int s4 = L >> 8;               // dispatch wave 0..3
    const int v  = g >> 5;               // 0..7
    // longest-first; per-CU slot set {31-v, 16+v, 15-v, v} sums to 66 iters
    const int qb = (s4 == 0) ? (31 - v) : (s4 == 1) ? (16 + v) : (s4 == 2) ? (15 - v) : v;
    const int bh = g & 31;
    const int b  = bh >> 2;
    const int h  = bh & 3;

    // ---- Q fragments straight from global (B-operand: B[n=q][k]) ----
    const ushort_t* Qp = Qb + ((size_t)(bh * SEQ + qb * 64 + wv * 16 + l15)) * HD + l4 * 8;
    const bfrag bq0 = *(const bfrag*)Qp;
    const bfrag bq1 = *(const bfrag*)(Qp + 32);

    // ---- staging geometry ----
    const ushort_t* Kbase = Kb  + (size_t)bh * SEQ * HD;
    const ushort_t* Vbase = Vtb + (size_t)bh * HD * SEQ;
    const int srow  = tid >> 3;            // 0..31
    const int sc    = tid & 7;             // logical 16B-chunk
    const int goffA = srow * 64 + sc * 8;              // K global (ushorts)
    const int voffA = srow * SEQ + sc * 8;             // V global
    const int soffA = srow * 64 + ((sc ^ (srow & 7)) * 8);   // swizzled LDS

    // ---- fragment read offsets (precomputed, swizzled) ----
    const int kf0 = l15 * 64 + ((l4 ^ e) * 8);   // + n*1024 ; ^32 for k-chunk 1
    const int pf0 = (wv * 16 + l15) * 64 + ((l4 ^ e) * 8);
    const int pp  = e >> 1;
    const int pwb = (wv * 16 + l15) * 64 + (((l4 >> 1) ^ (e & 1)) * 8) + (l4 & 1) * 4;

    // ---- prologue: tile 0 -> regs -> LDS buf0 ; tile 1 -> regs ----
    uint4 kK0, kK1, kV0, kV1;
    kK0 = *(const uint4*)&Kbase[goffA];
    kK1 = *(const uint4*)&Kbase[goffA + 32 * 64];
    kV0 = *(const uint4*)&Vbase[voffA];
    kV1 = *(const uint4*)&Vbase[voffA + 32 * SEQ];
    *(uint4*)&KV[soffA]          = kK0;
    *(uint4*)&KV[soffA + 2048]   = kK1;
    *(uint4*)&KV[8192 + soffA]        = kV0;
    *(uint4*)&KV[8192 + soffA + 2048] = kV1;
    if (qb >= 1) {
        kK0 = *(const uint4*)&Kbase[4096 + goffA];
        kK1 = *(const uint4*)&Kbase[4096 + goffA + 32 * 64];
        kV0 = *(const uint4*)&Vbase[64 + voffA];
        kV1 = *(const uint4*)&Vbase[64 + voffA + 32 * SEQ];
    }

    ffrag o[4];
    #pragma unroll
    for (int n = 0; n < 4; n++) o[n] = (ffrag){0.f, 0.f, 0.f, 0.f};
    float m_q = -INFINITY;
    float l_q = 0.f;
    const int qg_l = qb * 64 + wv * 16 + l15;

    for (int kt = 0; kt <= qb; kt++) {
        if (kt > 0) {
            // commit prefetched tile kt into buffer kt&1
            const int kb = (kt & 1) * 4096;
            *(uint4*)&KV[kb + soffA]          = kK0;
            *(uint4*)&KV[kb + soffA + 2048]   = kK1;
            *(uint4*)&KV[8192 + kb + soffA]        = kV0;
            *(uint4*)&KV[8192 + kb + soffA + 2048] = kV1;
            if (kt < qb) {   // issue loads for tile kt+1 (land during compute)
                const ushort_t* Kp  = Kbase + (kt + 1) * 4096;
                const ushort_t* Vtp = Vbase + (kt + 1) * 64;
                kK0 = *(const uint4*)&Kp[goffA];
                kK1 = *(const uint4*)&Kp[goffA + 32 * 64];
                kV0 = *(const uint4*)&Vtp[voffA];
                kV1 = *(const uint4*)&Vtp[voffA + 32 * SEQ];
            }
        }
        __syncthreads();   // the ONLY barrier in the iteration

        const ushort_t* Kbuf = KV + (kt & 1) * 4096;
        const ushort_t* Vbuf = KV + 8192 + (kt & 1) * 4096;

        // ---- S^T = K Q^T : s[n][r] = S[q=l15][k = n*16 + l4*4 + r] ----
        ffrag s[4];
        #pragma unroll
        for (int n = 0; n < 4; n++) {
            const bfrag ak0 = *(const bfrag*)&Kbuf[n * 1024 + kf0];
            const bfrag ak1 = *(const bfrag*)&Kbuf[n * 1024 + (kf0 ^ 32)];
            ffrag z = (ffrag){0.f, 0.f, 0.f, 0.f};
            z = __builtin_amdgcn_mfma_f32_16x16x32_bf16(ak0, bq0, z, 0, 0, 0);
            z = __builtin_amdgcn_mfma_f32_16x16x32_bf16(ak1, bq1, z, 0, 0, 0);
            s[n] = z;
        }
        if (kt == qb) {   // causal mask on the diagonal tile
            #pragma unroll
            for (int n = 0; n < 4; n++)
                #pragma unroll
                for (int r = 0; r < 4; r++)
                    if (kt * 64 + n * 16 + l4 * 4 + r > qg_l) s[n][r] = -INFINITY;
        }

        // ---- online softmax (exp2 domain) ----
        float mx = s[0][0];
        #pragma unroll
        for (int n = 0; n < 4; n++)
            #pragma unroll
            for (int r = 0; r < 4; r++) mx = fmaxf(mx, s[n][r]);
        mx = fmaxf(mx, __shfl_xor(mx, 16));
        mx = fmaxf(mx, __shfl_xor(mx, 32));
        const float mn = fmaxf(m_q, mx);
        const float alpha = __builtin_amdgcn_exp2f(m_q - mn);
        m_q = mn;

        float rs = 0.f;
        #pragma unroll
        for (int n = 0; n < 4; n++)
            #pragma unroll
            for (int r = 0; r < 4; r++) {
                const float p = __builtin_amdgcn_exp2f(s[n][r] - mn);
                s[n][r] = p;
                rs += p;
            }
        rs += __shfl_xor(rs, 16);
        rs += __shfl_xor(rs, 32);
        l_q = l_q * alpha + rs;

        // ---- pack P (bf16, A-layout, swizzled, wave-private rows) ----
        #pragma unroll
        for (int n = 0; n < 4; n++) {
            uint2 pk;
            pk.x = pack2(s[n][0], s[n][1]);
            pk.y = pack2(s[n][2], s[n][3]);
            *(uint2*)&Ps[pwb + ((n ^ pp) << 4)] = pk;
        }

        // ---- O *= alpha (row l4*4+r alpha via shuffle) ----
        #pragma unroll
        for (int r = 0; r < 4; r++) {
            const float ar = __shfl(alpha, l4 * 20 + r);
            #pragma unroll
            for (int n = 0; n < 4; n++) o[n][r] *= ar;
        }

        // ---- O += P @ V ----
        const bfrag ap0 = *(const bfrag*)&Ps[pf0];
        const bfrag ap1 = *(const bfrag*)&Ps[pf0 ^ 32];
        #pragma unroll
        for (int n = 0; n < 4; n++) {
            const bfrag bv0 = *(const bfrag*)&Vbuf[n * 1024 + kf0];
            const bfrag bv1 = *(const bfrag*)&Vbuf[n * 1024 + (kf0 ^ 32)];
            o[n] = __builtin_amdgcn_mfma_f32_16x16x32_bf16(ap0, bv0, o[n], 0, 0, 0);
            o[n] = __builtin_amdgcn_mfma_f32_16x16x32_bf16(ap1, bv1, o[n], 0, 0, 0);
        }
    }

    // ---- normalize + store O (bf16, [B,T,C]) ----
    const int tg = qb * 64 + wv * 16 + l4 * 4;
    ushort_t* op = out + (size_t)(b * SEQ) * CH + h * HD;
    #pragma unroll
    for (int r = 0; r < 4; r++) {
        const float lr = __shfl(l_q, l4 * 20 + r);
        const float li = 1.0f / lr;
        #pragma unroll
        for (int n = 0; n < 4; n++)
            op[(size_t)(tg + r) * CH + n * 16 + l15] = f2bf(o[n][r] * li);
    }
}

// ---------------------------------------------------------------------------
// Proj MFMA GEMM: attn_b(16384x256) @ WprojT^T + bproj -> fp32 out.
// 64x64 tile (4 waves as 2x2 of 32x32), grid 1024 -> 4 blocks/CU.
// Double-buffered LDS (1 barrier/step) + register prefetch.
// ---------------------------------------------------------------------------
__global__ __launch_bounds__(256) void proj_mfma_kernel(
    const ushort_t* __restrict__ Ab, const ushort_t* __restrict__ Wt,
    const float* __restrict__ bias, float* __restrict__ O) {
    __shared__ ushort_t smem[2 * 128 * GLS];   // [buf][A(64) | B(64)]

    const int tid = threadIdx.x;
    const int wv  = tid >> 6;
    const int ln  = tid & 63;
    const int l15 = ln & 15;
    const int l4  = ln >> 4;
    const int wr  = wv >> 1;          // 0..1 -> 32-row band
    const int wc  = wv & 1;           // 0..1 -> 32-col band
    const int n0  = blockIdx.x * 64;
    const int m0  = blockIdx.y * 64;

    const int srow = tid >> 3;            // 0..31
    const int sc8  = (tid & 7) * 8;

    ffrag acc[2][2];
    #pragma unroll
    for (int i = 0; i < 2; i++)
        #pragma unroll
        for (int j = 0; j < 2; j++) acc[i][j] = (ffrag){0.f, 0.f, 0.f, 0.f};

    uint4 ra0, ra1, rb0, rb1;
    ra0 = *(const uint4*)&Ab[(size_t)(m0 + srow) * CH + sc8];
    ra1 = *(const uint4*)&Ab[(size_t)(m0 + 32 + srow) * CH + sc8];
    rb0 = *(const uint4*)&Wt[(n0 + srow) * CH + sc8];
    rb1 = *(const uint4*)&Wt[(n0 + 32 + srow) * CH + sc8];

    for (int s = 0; s < 4; s++) {
        ushort_t* As = smem + (s & 1) * (128 * GLS);
        ushort_t* Bs = As + 64 * GLS;
        *(uint4*)&As[srow * GLS + sc8]        = ra0;
        *(uint4*)&As[(32 + srow) * GLS + sc8] = ra1;
        *(uint4*)&Bs[srow * GLS + sc8]        = rb0;
        *(uint4*)&Bs[(32 + srow) * GLS + sc8] = rb1;
        __syncthreads();
        if (s < 3) {
            const int k0 = (s + 1) * 64;
            ra0 = *(const uint4*)&Ab[(size_t)(m0 + srow) * CH + k0 + sc8];
            ra1 = *(const uint4*)&Ab[(size_t)(m0 + 32 + srow) * CH + k0 + sc8];
            rb0 = *(const uint4*)&Wt[(n0 + srow) * CH + k0 + sc8];
            rb1 = *(const uint4*)&Wt[(n0 + 32 + srow) * CH + k0 + sc8];
        }
        #pragma unroll
        for (int kk = 0; kk < 64; kk += 32) {
            bfrag a[2], bfr[2];
            #pragma unroll
            for (int i = 0; i < 2; i++)
                a[i] = *(const bfrag*)&As[(wr * 32 + i * 16 + l15) * GLS + kk + l4 * 8];
            #pragma unroll
            for (int j = 0; j < 2; j++)
                bfr[j] = *(const bfrag*)&Bs[(wc * 32 + j * 16 + l15) * GLS + kk + l4 * 8];
            #pragma unroll
            for (int i = 0; i < 2; i++)
                #pragma unroll
                for (int j = 0; j < 2; j++)
                    acc[i][j] = __builtin_amdgcn_mfma_f32_16x16x32_bf16(a[i], bfr[j], acc[i][j], 0, 0, 0);
        }
        __syncthreads();
    }

    #pragma unroll
    for (int j = 0; j < 2; j++) {
        const int n = n0 + wc * 32 + j * 16 + l15;
        const float bj = bias[n];
        #pragma unroll
        for (int i = 0; i < 2; i++) {
            const int m = m0 + wr * 32 + i * 16 + l4 * 4;
            #pragma unroll
            for (int r = 0; r < 4; r++)
                O[(size_t)(m + r) * CH + n] = acc[i][j][r] + bj;
        }
    }
}

extern "C" void kernel_launch(void* const* d_in, const int* in_sizes, int n_in,
                              void* d_out, int out_size, void* d_ws, size_t ws_size,
                              hipStream_t stream) {
    const float* x     = (const float*)d_in[0];
    const float* Wqkv  = (const float*)d_in[1];
    const float* bqkv  = (const float*)d_in[2];
    const float* Wproj = (const float*)d_in[3];
    const float* bproj = (const float*)d_in[4];
    float* out = (float*)d_out;

    const size_t BHTD = (size_t)BATCH * NH * SEQ * HD;   // 4,194,304
    ushort_t* WqkvT  = (ushort_t*)d_ws;
    ushort_t* WprojT = WqkvT + (size_t)3 * CH * CH;
    ushort_t* Qb     = WprojT + (size_t)CH * CH;
    ushort_t* Kb     = Qb + BHTD;
    ushort_t* Vtb    = Kb + BHTD;
    ushort_t* attn_b = Vtb + BHTD;

    const int M = BATCH * SEQ;   // 16384

    {
        const int total = WQN + WPN;
        prep_kernel<<<(total + 255) / 256, 256, 0, stream>>>(Wqkv, Wproj, WqkvT, WprojT);
    }
    {
        dim3 grid((3 * CH) / 128, M / 128);
        qkv_mfma_kernel<<<grid, 256, 0, stream>>>(x, WqkvT, bqkv, Qb, Kb, Vtb);
    }
    {
        attn_mfma_kernel<<<dim3(NQB * BATCH * NH), 256, 0, stream>>>(Qb, Kb, Vtb, attn_b);
    }
    {
        dim3 grid(CH / 64, M / 64);
        proj_mfma_kernel<<<grid, 256, 0, stream>>>(attn_b, WprojT, bproj, out);
    }
}